// Round 3
// baseline (586.566 us; speedup 1.0000x reference)
//
#include <hip/hip_runtime.h>

#define T_LEN 4096
#define KS    16

#define ALPHA_F 0.9048374180359595f
#define BETA_F  0.09516258196404048f
#define THETA_F 0.5f

// Full-wave (64-lane) max, result in ALL lanes.
// 4 fused DPP max levels (row of 16), then permlane32_swap / permlane16_swap
// (gfx950) + max for the cross-row levels. Manual s_nop 1 before every
// DPP/permlane consumer: VALU->DPP read requires 2 wait states and the
// compiler cannot see inside this asm block (this was R2's bug).
// Swap levels are direction-robust: both operands enter with the same value,
// so max(a,b) = max(own, partner) whichever way the halves move.
__device__ __forceinline__ float wave64_max_all(float v) {
  float m, t;
  asm("s_nop 1\n\t"
      "v_max_f32 %0, %2, %2 quad_perm:[1,0,3,2] row_mask:0xf bank_mask:0xf\n\t"
      "s_nop 1\n\t"
      "v_max_f32 %0, %0, %0 quad_perm:[2,3,0,1] row_mask:0xf bank_mask:0xf\n\t"
      "s_nop 1\n\t"
      "v_max_f32 %0, %0, %0 row_half_mirror row_mask:0xf bank_mask:0xf\n\t"
      "s_nop 1\n\t"
      "v_max_f32 %0, %0, %0 row_mirror row_mask:0xf bank_mask:0xf\n\t"
      "v_mov_b32 %1, %0\n\t"
      "s_nop 1\n\t"
      "v_permlane32_swap_b32 %1, %0\n\t"
      "s_nop 1\n\t"
      "v_max_f32 %0, %0, %1\n\t"
      "v_mov_b32 %1, %0\n\t"
      "s_nop 1\n\t"
      "v_permlane16_swap_b32 %1, %0\n\t"
      "s_nop 1\n\t"
      "v_max_f32 %0, %0, %1"
      : "=&v"(m), "=&v"(t)
      : "v"(v));
  return m;
}

__global__ __launch_bounds__(64, 1)
void convlif_wta_kernel(const float* __restrict__ x, const float* __restrict__ W,
                        float* __restrict__ out) {
  const int b    = blockIdx.x;
  const int lane = threadIdx.x;   // channel k

  __shared__ float tile[64][65];  // [k][t&63], +1 pad -> 2-way aliasing max (free)

  // per-lane conv weights W[k][0..15]
  float w[KS];
  {
    const float4* w4 = reinterpret_cast<const float4*>(W + lane * KS);
    #pragma unroll
    for (int q = 0; q < 4; ++q) {
      float4 a = w4[q];
      w[4*q+0] = a.x; w[4*q+1] = a.y; w[4*q+2] = a.z; w[4*q+3] = a.w;
    }
  }

  const float4* xv4 = reinterpret_cast<const float4*>(x + (size_t)b * T_LEN);

  // rolling x window: xw[j] = x[tb-15+j], j = 0..30 (x[<0] = 0)
  float xw[31];
  float v = 0.0f;

  for (int t0 = 0; t0 < T_LEN; t0 += 64) {
    #pragma unroll
    for (int c = 0; c < 4; ++c) {
      const int tb = t0 + 16 * c;
      if (tb == 0) {
        #pragma unroll
        for (int j = 0; j < 15; ++j) xw[j] = 0.0f;
      } else {
        #pragma unroll
        for (int j = 0; j < 15; ++j) xw[j] = xw[j + 16];
      }
      // wave-uniform loads of x[tb .. tb+15]
      #pragma unroll
      for (int q = 0; q < 4; ++q) {
        float4 a = xv4[(tb >> 2) + q];
        xw[15+4*q+0] = a.x; xw[15+4*q+1] = a.y;
        xw[15+4*q+2] = a.z; xw[15+4*q+3] = a.w;
      }

      #pragma unroll
      for (int i = 0; i < 16; ++i) {
        // causal conv for t = tb+i (independent of v -> latency shadow)
        float u = w[0] * xw[i];
        #pragma unroll
        for (int j = 1; j < KS; ++j) u = fmaf(w[j], xw[i + j], u);
        float bu = BETA_F * u;            // off-path

        // leak + input (same arithmetic as the passing R1 kernel)
        v = fmaf(ALPHA_F, v, bu);

        // off-critical-path precompute (depends only on own v)
        float vm  = v - THETA_F;          // exact; (vm>=0) <=> (v>=theta)
        bool  cth = (vm >= 0.0f);
        float sel = cth ? vm : v;         // next-v if I am the winner
        float s01 = cth ? 1.0f : 0.0f;    // spike value if I am the winner

        // critical path: 10-instr fused reduce -> cmp -> cndmask -> mbcnt x2 -> cmp
        float m = wave64_max_all(v);

        unsigned long long eq = __ballot(v == m);   // v_cmp_eq_f32 -> sgpr pair
        unsigned init = (v == m) ? 0u : 1u;         // same compare, cndmask
        unsigned cnt = __builtin_amdgcn_mbcnt_hi(
            (unsigned)(eq >> 32),
            __builtin_amdgcn_mbcnt_lo((unsigned)eq, init));
        bool win = (cnt == 0u);  // eq AND no eq-lane below me (first-index tie-break)

        tile[lane][(tb + i) & 63] = win ? s01 : 0.0f;
        v = win ? sel : v;
      }
    }

    // flush 64 timesteps, coalesced along t
    float* ob = out + ((size_t)b * 64) * T_LEN + t0 + lane;
    #pragma unroll 8
    for (int r = 0; r < 64; ++r) {
      ob[(size_t)r * T_LEN] = tile[r][lane];
    }
  }
}

extern "C" void kernel_launch(void* const* d_in, const int* in_sizes, int n_in,
                              void* d_out, int out_size, void* d_ws, size_t ws_size,
                              hipStream_t stream) {
  const float* x   = (const float*)d_in[0];
  const float* W   = (const float*)d_in[1];
  float*       out = (float*)d_out;
  convlif_wta_kernel<<<dim3(256), dim3(64), 0, stream>>>(x, W, out);
}

// Round 4
// 433.010 us; speedup vs baseline: 1.3546x; 1.3546x over previous
//
#include <hip/hip_runtime.h>

#define T_LEN 4096
#define KS    16

#define ALPHA_F 0.9048374180359595f
#define BETA_F  0.09516258196404048f
#define THETA_F 0.5f

// Full-wave (64-lane) max, result in ALL lanes. 4 fused DPP max levels, then
// permlane32_swap / permlane16_swap + max. Manual s_nop 1 before every
// DPP/permlane consumer (VALU->DPP needs 2 wait states; compiler can't see
// inside the asm block). Verbatim from the passing R3 kernel.
__device__ __forceinline__ float wave64_max_all(float v) {
  float m, t;
  asm("s_nop 1\n\t"
      "v_max_f32 %0, %2, %2 quad_perm:[1,0,3,2] row_mask:0xf bank_mask:0xf\n\t"
      "s_nop 1\n\t"
      "v_max_f32 %0, %0, %0 quad_perm:[2,3,0,1] row_mask:0xf bank_mask:0xf\n\t"
      "s_nop 1\n\t"
      "v_max_f32 %0, %0, %0 row_half_mirror row_mask:0xf bank_mask:0xf\n\t"
      "s_nop 1\n\t"
      "v_max_f32 %0, %0, %0 row_mirror row_mask:0xf bank_mask:0xf\n\t"
      "v_mov_b32 %1, %0\n\t"
      "s_nop 1\n\t"
      "v_permlane32_swap_b32 %1, %0\n\t"
      "s_nop 1\n\t"
      "v_max_f32 %0, %0, %1\n\t"
      "v_mov_b32 %1, %0\n\t"
      "s_nop 1\n\t"
      "v_permlane16_swap_b32 %1, %0\n\t"
      "s_nop 1\n\t"
      "v_max_f32 %0, %0, %1"
      : "=&v"(m), "=&v"(t)
      : "v"(v));
  return m;
}

__global__ __launch_bounds__(64, 1)
void convlif_wta_kernel(const float* __restrict__ x, const float* __restrict__ W,
                        float* __restrict__ out) {
  const int b    = blockIdx.x;
  const int lane = threadIdx.x;   // channel k

  __shared__ float tile[64][65];  // [k][t&63], +1 pad

  // per-lane conv weights W[k][0..15]
  float w[KS];
  {
    const float4* w4 = reinterpret_cast<const float4*>(W + lane * KS);
    #pragma unroll
    for (int q = 0; q < 4; ++q) {
      float4 a = w4[q];
      w[4*q+0] = a.x; w[4*q+1] = a.y; w[4*q+2] = a.z; w[4*q+3] = a.w;
    }
  }

  const float4* xv4 = reinterpret_cast<const float4*>(x + (size_t)b * T_LEN);

  // rolling x window: xw[j] = x[tb-15+j], j = 0..30 (x[<0] = 0)
  float xw[31];
  // next-chunk prefetch registers (loaded one chunk ahead -> no vmcnt stall)
  float4 nxt0 = xv4[0], nxt1 = xv4[1], nxt2 = xv4[2], nxt3 = xv4[3];

  float v = 0.0f;

  for (int t0 = 0; t0 < T_LEN; t0 += 64) {
    #pragma unroll
    for (int c = 0; c < 4; ++c) {
      const int tb = t0 + 16 * c;
      if (tb == 0) {
        #pragma unroll
        for (int j = 0; j < 15; ++j) xw[j] = 0.0f;
      } else {
        #pragma unroll
        for (int j = 0; j < 15; ++j) xw[j] = xw[j + 16];
      }
      xw[15]=nxt0.x; xw[16]=nxt0.y; xw[17]=nxt0.z; xw[18]=nxt0.w;
      xw[19]=nxt1.x; xw[20]=nxt1.y; xw[21]=nxt1.z; xw[22]=nxt1.w;
      xw[23]=nxt2.x; xw[24]=nxt2.y; xw[25]=nxt2.z; xw[26]=nxt2.w;
      xw[27]=nxt3.x; xw[28]=nxt3.y; xw[29]=nxt3.z; xw[30]=nxt3.w;

      // issue next chunk's loads now (16 steps of slack; clamped on last chunk,
      // result unused there)
      {
        int nb = tb + 16; if (nb > T_LEN - 16) nb = T_LEN - 16;
        nxt0 = xv4[(nb >> 2) + 0]; nxt1 = xv4[(nb >> 2) + 1];
        nxt2 = xv4[(nb >> 2) + 2]; nxt3 = xv4[(nb >> 2) + 3];
      }

      // phase A: all 16 conv outputs. 16 INDEPENDENT chains -> issue-bound.
      // Inner summation order identical to the passing R1/R3 kernels.
      float bu[16];
      #pragma unroll
      for (int i = 0; i < 16; ++i) {
        float u = w[0] * xw[i];
        #pragma unroll
        for (int j = 1; j < KS; ++j) u = fmaf(w[j], xw[i + j], u);
        bu[i] = BETA_F * u;
      }

      // phase B: serial LIF + WTA (the true recurrence)
      #pragma unroll
      for (int i = 0; i < 16; ++i) {
        v = fmaf(ALPHA_F, v, bu[i]);          // same arithmetic as R3
        float vm = v - THETA_F;               // exact; (vm>=0) <=> (v>=theta)

        unsigned long long over = __ballot(v >= THETA_F);  // wave-uniform
        if (over == 0ull) {
          // no channel crossed theta: no spike, no reset
          tile[lane][(tb + i) & 63] = 0.0f;
        } else {
          int wl;
          if ((over & (over - 1ull)) != 0ull) {
            // >=2 candidates: winner = first lane attaining the global max
            float m = wave64_max_all(v);
            unsigned long long eq = __ballot(v == m);
            wl = __builtin_ctzll(eq);
          } else {
            // exactly one lane >= theta: it IS the argmax (any tying lane
            // would also be >= theta), and ctz gives the first index
            wl = __builtin_ctzll(over);
          }
          bool win = (lane == wl);
          tile[lane][(tb + i) & 63] = win ? 1.0f : 0.0f;
          v = win ? vm : v;                   // v - s*theta, exact
        }
      }
    }

    // flush 64 timesteps, coalesced along t
    float* ob = out + ((size_t)b * 64) * T_LEN + t0 + lane;
    #pragma unroll 8
    for (int r = 0; r < 64; ++r) {
      ob[(size_t)r * T_LEN] = tile[r][lane];
    }
  }
}

extern "C" void kernel_launch(void* const* d_in, const int* in_sizes, int n_in,
                              void* d_out, int out_size, void* d_ws, size_t ws_size,
                              hipStream_t stream) {
  const float* x   = (const float*)d_in[0];
  const float* W   = (const float*)d_in[1];
  float*       out = (float*)d_out;
  convlif_wta_kernel<<<dim3(256), dim3(64), 0, stream>>>(x, W, out);
}

// Round 5
// 278.400 us; speedup vs baseline: 2.1069x; 1.5554x over previous
//
#include <hip/hip_runtime.h>

#define T_LEN  4096
#define KS     16
#define NCHUNK 256      // T_LEN / 16
#define LEAD   6        // producer runs 6 chunks ahead
#define SLOTS  8        // LDS ring slots (power of 2 > LEAD)
#define BU_PAD 20       // row stride in dwords (4-aligned, bank-spreading)

#define ALPHA_F 0.9048374180359595f
#define BETA_F  0.09516258196404048f
#define THETA_F 0.5f

// Full-wave (64-lane) max, result in ALL lanes. 4 fused DPP max levels, then
// permlane32_swap / permlane16_swap + max. Manual s_nop 1 before every
// DPP/permlane consumer (VALU->DPP needs 2 wait states; compiler can't see
// inside the asm block). Verbatim from the passing R3/R4 kernels.
__device__ __forceinline__ float wave64_max_all(float v) {
  float m, t;
  asm("s_nop 1\n\t"
      "v_max_f32 %0, %2, %2 quad_perm:[1,0,3,2] row_mask:0xf bank_mask:0xf\n\t"
      "s_nop 1\n\t"
      "v_max_f32 %0, %0, %0 quad_perm:[2,3,0,1] row_mask:0xf bank_mask:0xf\n\t"
      "s_nop 1\n\t"
      "v_max_f32 %0, %0, %0 row_half_mirror row_mask:0xf bank_mask:0xf\n\t"
      "s_nop 1\n\t"
      "v_max_f32 %0, %0, %0 row_mirror row_mask:0xf bank_mask:0xf\n\t"
      "v_mov_b32 %1, %0\n\t"
      "s_nop 1\n\t"
      "v_permlane32_swap_b32 %1, %0\n\t"
      "s_nop 1\n\t"
      "v_max_f32 %0, %0, %1\n\t"
      "v_mov_b32 %1, %0\n\t"
      "s_nop 1\n\t"
      "v_permlane16_swap_b32 %1, %0\n\t"
      "s_nop 1\n\t"
      "v_max_f32 %0, %0, %1"
      : "=&v"(m), "=&v"(t)
      : "v"(v));
  return m;
}

__global__ __launch_bounds__(192, 1)
void convlif_wta_kernel(const float* __restrict__ x, const float* __restrict__ W,
                        float* __restrict__ out) {
  const int b    = blockIdx.x;
  const int wave = threadIdx.x >> 6;   // 0,1 = conv producers; 2 = LIF consumer
  const int lane = threadIdx.x & 63;   // channel k

  // producer->consumer ring: bu[slot][channel][i] (i = step within chunk)
  __shared__ float bu_lds[SLOTS][64][BU_PAD];   // 40 KB

  float* outB = out + (size_t)b * 64 * T_LEN;

  // ---- cooperative zero-fill of this block's 1 MB output region ----------
  {
    const float4 z = make_float4(0.f, 0.f, 0.f, 0.f);
    float4* o4 = reinterpret_cast<float4*>(outB);
    for (int i = threadIdx.x; i < (64 * T_LEN) / 4; i += 192) o4[i] = z;
  }
  // drain stores so later sparse 1.0 writes (same block, same L2) order after
  asm volatile("s_waitcnt vmcnt(0)" ::: "memory");
  __syncthreads();

  if (wave < 2) {
    // ================= producers: causal conv, alternating chunks ========
    float w[KS];
    {
      const float4* w4 = reinterpret_cast<const float4*>(W + lane * KS);
      #pragma unroll
      for (int q = 0; q < 4; ++q) {
        float4 a = w4[q];
        w[4*q+0] = a.x; w[4*q+1] = a.y; w[4*q+2] = a.z; w[4*q+3] = a.w;
      }
    }
    const float4* xv4 = reinterpret_cast<const float4*>(x + (size_t)b * T_LEN);

    for (int s = 0; s < NCHUNK + LEAD; ++s) {
      if (s < NCHUNK && (s & 1) == wave) {
        const int c = s;
        // xf[m] = x[16c-16+m], m = 0..31 (x[<0] treated as 0)
        float xf[32];
        if (c == 0) {
          #pragma unroll
          for (int m = 0; m < 16; ++m) xf[m] = 0.0f;
        } else {
          const int b4 = 4 * c - 4;
          #pragma unroll
          for (int q = 0; q < 4; ++q) {
            float4 a = xv4[b4 + q];
            xf[4*q+0] = a.x; xf[4*q+1] = a.y; xf[4*q+2] = a.z; xf[4*q+3] = a.w;
          }
        }
        #pragma unroll
        for (int q = 0; q < 4; ++q) {
          float4 a = xv4[4*c + q];
          xf[16+4*q+0] = a.x; xf[16+4*q+1] = a.y;
          xf[16+4*q+2] = a.z; xf[16+4*q+3] = a.w;
        }

        // u[t=16c+i] = sum_j w[j]*x[t-15+j] ; summation order identical to R4
        float u[16];
        #pragma unroll
        for (int i = 0; i < 16; ++i) {
          float acc = w[0] * xf[1 + i];
          #pragma unroll
          for (int j = 1; j < KS; ++j) acc = fmaf(w[j], xf[1 + i + j], acc);
          u[i] = BETA_F * acc;
        }

        float4* dst = reinterpret_cast<float4*>(&bu_lds[c & (SLOTS-1)][lane][0]);
        dst[0] = make_float4(u[0],  u[1],  u[2],  u[3]);
        dst[1] = make_float4(u[4],  u[5],  u[6],  u[7]);
        dst[2] = make_float4(u[8],  u[9],  u[10], u[11]);
        dst[3] = make_float4(u[12], u[13], u[14], u[15]);
      }
      __syncthreads();
    }
  } else {
    // ================= consumer: serial LIF + WTA recurrence =============
    float v = 0.0f;
    float4 b0, b1, b2, b3;   // current chunk's bu (prefetched)

    for (int s = 0; s < NCHUNK + LEAD; ++s) {
      if (s >= LEAD) {
        const int c = s - LEAD;
        if (c == 0) {
          const float4* src = reinterpret_cast<const float4*>(&bu_lds[0][lane][0]);
          b0 = src[0]; b1 = src[1]; b2 = src[2]; b3 = src[3];
        }
        float bu[16] = { b0.x, b0.y, b0.z, b0.w,  b1.x, b1.y, b1.z, b1.w,
                         b2.x, b2.y, b2.z, b2.w,  b3.x, b3.y, b3.z, b3.w };

        #pragma unroll
        for (int i = 0; i < 16; ++i) {
          v = fmaf(ALPHA_F, v, bu[i]);          // same arithmetic as R4
          float vm = v - THETA_F;               // exact; (vm>=0) <=> (v>=theta)

          unsigned long long over = __ballot(v >= THETA_F);
          if (over != 0ull) {
            int wl;
            if ((over & (over - 1ull)) != 0ull) {
              // >=2 candidates: winner = first lane attaining the global max
              float m = wave64_max_all(v);
              unsigned long long eq = __ballot(v == m);
              wl = __builtin_ctzll(eq);
            } else {
              // exactly one lane >= theta: it IS the argmax (any tying lane
              // would also be >= theta); first-index trivially preserved
              wl = __builtin_ctzll(over);
            }
            if (lane == wl) {
              outB[(size_t)wl * T_LEN + (c * 16 + i)] = 1.0f;  // sparse spike
              v = vm;                                          // v - theta, exact
            }
          }
          // no-spike: nothing to store (zeros prefilled), v unchanged
        }

        // prefetch next chunk's bu (produced >= 1 barrier ago; slot safe)
        if (c + 1 < NCHUNK) {
          const float4* src =
              reinterpret_cast<const float4*>(&bu_lds[(c + 1) & (SLOTS-1)][lane][0]);
          b0 = src[0]; b1 = src[1]; b2 = src[2]; b3 = src[3];
        }
      }
      __syncthreads();
    }
  }
}

extern "C" void kernel_launch(void* const* d_in, const int* in_sizes, int n_in,
                              void* d_out, int out_size, void* d_ws, size_t ws_size,
                              hipStream_t stream) {
  const float* x   = (const float*)d_in[0];
  const float* W   = (const float*)d_in[1];
  float*       out = (float*)d_out;
  convlif_wta_kernel<<<dim3(256), dim3(192), 0, stream>>>(x, W, out);
}